// Round 9
// baseline (654.368 us; speedup 1.0000x reference)
//
#include <hip/hip_runtime.h>
#include <hip/hip_bf16.h>

// Problem constants
#define OUT_F 11008   // N
#define IN_F  4096    // K
#define M_DIM 4096    // 4 * 1024

typedef __attribute__((ext_vector_type(8))) short bf16x8;          // MFMA A/B frag
typedef __attribute__((ext_vector_type(4))) float f32x4;           // MFMA C/D frag
typedef __attribute__((ext_vector_type(8))) unsigned short us8;    // 16B of bf16 bits

// ---------------------------------------------------------------------------
// Kernel 1 (fused prep):  (unchanged from R8 — harness-verified)
//  blocks [0,8192): x fp32 -> bf16 (8 elems/thread).
//  blocks [8192, 8192+688): repack 2-bit weights fragment-major:
//    pw2 (as ushort): [rg 688][kt 64][h 2][quad 4][mrow 16]
// ---------------------------------------------------------------------------
__device__ __forceinline__ unsigned short f2bf_rne(float f) {
    unsigned u = __builtin_bit_cast(unsigned, f);
    u += 0x7fffu + ((u >> 16) & 1u);
    return (unsigned short)(u >> 16);
}

__global__ void prep_kernel(const float* __restrict__ x,
                            unsigned short* __restrict__ xb,
                            const int* __restrict__ pw,
                            unsigned short* __restrict__ pw2) {
    if (blockIdx.x < 8192) {
        size_t i = ((size_t)blockIdx.x * blockDim.x + threadIdx.x) * 8;
        float4 a = *(const float4*)(x + i);
        float4 b = *(const float4*)(x + i + 4);
        us8 o;
        o[0] = f2bf_rne(a.x); o[1] = f2bf_rne(a.y);
        o[2] = f2bf_rne(a.z); o[3] = f2bf_rne(a.w);
        o[4] = f2bf_rne(b.x); o[5] = f2bf_rne(b.y);
        o[6] = f2bf_rne(b.z); o[7] = f2bf_rne(b.w);
        *(us8*)(xb + i) = o;
    } else {
        __shared__ unsigned char lb[16 * 1028];
        const int rg = blockIdx.x - 8192;        // 0..687
        const int t  = threadIdx.x;              // 0..255
        const int4* src = (const int4*)(pw + (size_t)rg * 16384);
#pragma unroll
        for (int r = 0; r < 16; ++r) {
            int4 v = src[r * 256 + t];
            lb[r * 1028 + t * 4 + 0] = (unsigned char)(v.x & 0xFF);
            lb[r * 1028 + t * 4 + 1] = (unsigned char)(v.y & 0xFF);
            lb[r * 1028 + t * 4 + 2] = (unsigned char)(v.z & 0xFF);
            lb[r * 1028 + t * 4 + 3] = (unsigned char)(v.w & 0xFF);
        }
        __syncthreads();
        unsigned short* dst = pw2 + (size_t)rg * 8192;
#pragma unroll
        for (int i = 0; i < 32; ++i) {
            const int u    = i * 256 + t;
            const int kt   = u >> 7;
            const int h    = (u >> 6) & 1;
            const int qd   = (u >> 4) & 3;
            const int mrow = u & 15;
            const int c0   = kt * 16 + h * 8 + qd * 2;
            dst[u] = (unsigned short)(lb[mrow * 1028 + c0] |
                                      (lb[mrow * 1028 + c0 + 1] << 8));
        }
    }
}

// ---------------------------------------------------------------------------
// Kernel 2: bf16 GEMM, 256x256 tile, BK=64, 8 waves (2x4 of 128x64),
// FAITHFUL m201 C-QUADRANT 4-PHASE SCHEDULE + packed-B-in-regs (round-9).
//
// Cross-round evidence (R0-R8): seven structures pinned at 42-43% MfmaUtil;
// FETCH varied 7x, VALU 2.6x, barriers 8x -- wall invariant.  The only
// >43% structure measured on this HW at 2 waves/SIMD is the m201 8-phase
// template (62%).  R1's port deviated: unbalanced phase reads (10/2/10/2),
// B through LDS, shallow vmcnt.  This version: C-quadrant phases (16 MFMA
// each, full K=64), balanced reads, B packed in regs (NO B LDS at all),
// A triple-buffered with one global_load_lds per phase and counted
// VMCNT(12) at tile end only, setprio(1) around MFMA (T5), lgkmcnt(0)+
// sched_barrier after each mid-phase barrier (rule 18).
//
// LDS: sA[3][2][256][32] = 96 KB triple buffer (A only).
//  - slot for (row, seg) = seg ^ ((row>>1)&3); frag reads 2-way = free.
//  - A staging linear-dest global_load_lds, source seg pre-swizzled.
//
// Per-tile schedule (bC=A(kt) published, bN=A(kt+1) in flight/landed,
// bS = target for A(kt+2); 12 vm-ops issued per tile: 4 stages + 8 npkb):
//  p0 (Qm0,Qn0): read aM0 (8 ds), unpack bN0 (4), stage#0 -> bS
//                | bar | lgkm0 | prio1 16 MFMA prio0 | bar
//  p1 (Qm0,Qn1): unpack bN1 (4), issue npkb(kt+1) x8, stage#1
//                | bar | lgkm0 | prio1 16 MFMA prio0 | bar
//  p2 (Qm1,Qn1): read aM1 (8 ds), stage#2
//                | bar | lgkm0 | prio1 16 MFMA prio0 | bar
//  p3 (Qm1,Qn0): stage#3 | bar | lgkm0 | prio1 16 MFMA prio0 |
//                pkb <- npkb (implicit vmcnt on npkb, ~2 phases old = free)
//                VMCNT(12)  [drains A(kt+1)'s 4 loads, issued last tile;
//                            keeps this tile's 12 in flight -- never 0]
//                bar        [publishes sA[bN] for kt+1]
// WAR on bS: its last reads were at kt-1 (it was bC then), consumed before
// kt-1's exit barrier.  RAW on bN: drained by VMCNT(12)+barrier at kt end.
// ---------------------------------------------------------------------------
#define LGKM0() do { asm volatile("s_waitcnt lgkmcnt(0)" ::: "memory"); \
                     __builtin_amdgcn_sched_barrier(0); } while (0)
#define VMCNT(n) do { asm volatile("s_waitcnt vmcnt(" #n ")" ::: "memory"); \
                      __builtin_amdgcn_sched_barrier(0); } while (0)

__device__ __forceinline__ void unpack_byte(unsigned b, unsigned& d_lo,
                                            unsigned& d_hi) {
    // byte b = 4 x 2-bit fields -> 4 bf16 {-1,0,1,2} (perm byte-LUT, HW-
    // validated R7/R8).  LUT: 0xBF80,0x0000,0x3F80,0x4000.
    const unsigned PA = 0x00800080u;   // lo-byte LUT
    const unsigned PB = 0x403F00BFu;   // hi-byte LUT
    unsigned m0 = (b & 0xFu) * 0x00404101u;
    unsigned s0 = (m0 & 0x03030303u) | 0x00040004u;
    d_lo = __builtin_amdgcn_perm(PA, PB, s0);
    unsigned m1 = (b >> 4) * 0x00404101u;
    unsigned s1 = (m1 & 0x03030303u) | 0x00040004u;
    d_hi = __builtin_amdgcn_perm(PA, PB, s1);
}

__device__ __forceinline__ bf16x8 unpack_us(unsigned short p) {
    unsigned d0, d1, d2, d3;
    unpack_byte(p & 0xFFu, d0, d1);
    unpack_byte((unsigned)p >> 8, d2, d3);
    uint4 u = (uint4){d0, d1, d2, d3};
    return __builtin_bit_cast(bf16x8, u);
}

__global__ __launch_bounds__(512, 2) void gemm_kernel(
    const unsigned short* __restrict__ A,   // [M_DIM][IN_F] bf16 bits
    const unsigned short* __restrict__ P,   // packed W [rg][kt][h][quad][mrow]
    float* __restrict__ C,                  // [M_DIM][OUT_F]
    const float* __restrict__ scale_ptr) {
    constexpr int K  = IN_F;
    constexpr int NN = OUT_F;
    constexpr int NT = K / 64;              // 64 K-tiles

    __shared__ unsigned short sA[3][2][256][32];   // 96 KB

    const int tid  = threadIdx.x;
    const int wave = tid >> 6;
    const int lane = tid & 63;
    const int quad = lane >> 4;
    const int mrow = lane & 15;
    const int sw   = quad ^ ((mrow >> 1) & 3);          // A frag-read slot

    const int srow = lane >> 2;                         // staging row-in-chunk
    const int sseg = (lane & 3) ^ ((lane >> 3) & 3);    // staging k-seg

    // XCD-bijective block swizzle (688 % 8 == 0).
    const int lin = blockIdx.x;             // 0..687
    const int xcd = lin & 7;
    const int q   = lin >> 3;               // 0..85
    const int bm  = xcd * 2 + q / 43;       // 0..15
    const int bn  = q % 43;                 // 0..42

    const int wm = (wave >> 2) * 128;       // wave M offset in tile
    const int wn = (wave & 3) * 64;         // wave N offset in tile

    const unsigned short* Ag = A + (size_t)bm * 256 * K;
    const int rgb = bn * 16 + (wn >> 4);
    const unsigned short* Pb = P + (size_t)rgb * 8192 + lane;  // hoisted base

    f32x4 acc[8][4];
#pragma unroll
    for (int i = 0; i < 8; i++)
#pragma unroll
        for (int j = 0; j < 4; j++) acc[i][j] = (f32x4){0.f, 0.f, 0.f, 0.f};

    // One global_load_lds of the A K-tile (part in 0..3 -> (c,h)).
    auto STAGE_A1 = [&](int nb, int kbase, int part) {
        const int c = part & 1, h = part >> 1;
        const int chunk = wave * 2 + c;
        const int grow  = chunk * 16 + srow;
        const unsigned short* src =
            Ag + (size_t)grow * K + kbase + h * 32 + sseg * 8;
        __builtin_amdgcn_global_load_lds(
            (const __attribute__((address_space(1))) void*)src,
            (__attribute__((address_space(3))) void*)
                (&sA[nb][h][0][0] + chunk * 512),
            16, 0, 0);
    };

    // Prologue: A(0)->buf0, A(1)->buf1 (in flight), pkb = packed(0).
#pragma unroll
    for (int p = 0; p < 4; ++p) STAGE_A1(0, 0, p);
#pragma unroll
    for (int p = 0; p < 4; ++p) STAGE_A1(1, 64, p);
    unsigned short pkb[8], npkb[8];
#pragma unroll
    for (int j = 0; j < 4; ++j)
#pragma unroll
        for (int h = 0; h < 2; ++h)
            pkb[j * 2 + h] = Pb[(size_t)j * 8192 + h * 64];
#pragma unroll
    for (int i = 0; i < 8; ++i) npkb[i] = 0;
    VMCNT(12);                 // A(0)'s 4 loads (oldest) landed
    __builtin_amdgcn_s_barrier();

    int bC = 0, bN = 1, bS = 2;
    bf16x8 a[4][2], b0[2][2], b1[2][2];

    for (int kt = 0; kt < NT; ++kt) {
        const bool pf1 = (kt + 1 < NT);
        const bool pf2 = (kt + 2 < NT);
        const int  kn2 = (kt + 2) * 64;

        // ---- p0: quadrant (m0, n0) --------------------------------------
#pragma unroll
        for (int t = 0; t < 4; ++t)
#pragma unroll
            for (int h = 0; h < 2; ++h)
                a[t][h] = *(const bf16x8*)&sA[bC][h][wm + t * 16 + mrow][sw * 8];
#pragma unroll
        for (int jj = 0; jj < 2; ++jj)
#pragma unroll
            for (int h = 0; h < 2; ++h)
                b0[jj][h] = unpack_us(pkb[jj * 2 + h]);
        if (pf2) STAGE_A1(bS, kn2, 0);
        __builtin_amdgcn_s_barrier();
        LGKM0();
        __builtin_amdgcn_s_setprio(1);
#pragma unroll
        for (int h = 0; h < 2; ++h)
#pragma unroll
            for (int t = 0; t < 4; ++t)
#pragma unroll
                for (int jj = 0; jj < 2; ++jj)
                    acc[t][jj] = __builtin_amdgcn_mfma_f32_16x16x32_bf16(
                        a[t][h], b0[jj][h], acc[t][jj], 0, 0, 0);
        __builtin_amdgcn_s_setprio(0);
        __builtin_amdgcn_s_barrier();

        // ---- p1: quadrant (m0, n1) --------------------------------------
#pragma unroll
        for (int jj = 0; jj < 2; ++jj)
#pragma unroll
            for (int h = 0; h < 2; ++h)
                b1[jj][h] = unpack_us(pkb[(2 + jj) * 2 + h]);
        if (pf1) {
            const unsigned short* Pk = Pb + (size_t)(kt + 1) * 128;
#pragma unroll
            for (int j = 0; j < 4; ++j)
#pragma unroll
                for (int h = 0; h < 2; ++h)
                    npkb[j * 2 + h] = Pk[(size_t)j * 8192 + h * 64];
        }
        if (pf2) STAGE_A1(bS, kn2, 1);
        __builtin_amdgcn_s_barrier();
        LGKM0();
        __builtin_amdgcn_s_setprio(1);
#pragma unroll
        for (int h = 0; h < 2; ++h)
#pragma unroll
            for (int t = 0; t < 4; ++t)
#pragma unroll
                for (int jj = 0; jj < 2; ++jj)
                    acc[t][2 + jj] = __builtin_amdgcn_mfma_f32_16x16x32_bf16(
                        a[t][h], b1[jj][h], acc[t][2 + jj], 0, 0, 0);
        __builtin_amdgcn_s_setprio(0);
        __builtin_amdgcn_s_barrier();

        // ---- p2: quadrant (m1, n1) --------------------------------------
#pragma unroll
        for (int t = 0; t < 4; ++t)
#pragma unroll
            for (int h = 0; h < 2; ++h)
                a[t][h] = *(const bf16x8*)&sA[bC][h][wm + 64 + t * 16 + mrow][sw * 8];
        if (pf2) STAGE_A1(bS, kn2, 2);
        __builtin_amdgcn_s_barrier();
        LGKM0();
        __builtin_amdgcn_s_setprio(1);
#pragma unroll
        for (int h = 0; h < 2; ++h)
#pragma unroll
            for (int t = 0; t < 4; ++t)
#pragma unroll
                for (int jj = 0; jj < 2; ++jj)
                    acc[4 + t][2 + jj] = __builtin_amdgcn_mfma_f32_16x16x32_bf16(
                        a[t][h], b1[jj][h], acc[4 + t][2 + jj], 0, 0, 0);
        __builtin_amdgcn_s_setprio(0);
        __builtin_amdgcn_s_barrier();

        // ---- p3: quadrant (m1, n0) --------------------------------------
        if (pf2) STAGE_A1(bS, kn2, 3);
        __builtin_amdgcn_s_barrier();
        LGKM0();
        __builtin_amdgcn_s_setprio(1);
#pragma unroll
        for (int h = 0; h < 2; ++h)
#pragma unroll
            for (int t = 0; t < 4; ++t)
#pragma unroll
                for (int jj = 0; jj < 2; ++jj)
                    acc[4 + t][jj] = __builtin_amdgcn_mfma_f32_16x16x32_bf16(
                        a[t][h], b0[jj][h], acc[4 + t][jj], 0, 0, 0);
        __builtin_amdgcn_s_setprio(0);

        // tile end: rotate pkb (npkb ~2 phases old -> wait is free),
        // counted drain of A(kt+1), publish, rotate buffers.
#pragma unroll
        for (int i = 0; i < 8; ++i) pkb[i] = npkb[i];
        VMCNT(12);
        __builtin_amdgcn_s_barrier();
        const int t0 = bC; bC = bN; bN = bS; bS = t0;
    }

    // Epilogue: C/D layout col=lane&15, row=quad*4+reg
    const float scale = *scale_ptr;
    float* Cg = C + (size_t)(bm * 256 + wm) * NN + bn * 256 + wn;
#pragma unroll
    for (int i = 0; i < 8; ++i) {
#pragma unroll
        for (int j = 0; j < 4; ++j) {
#pragma unroll
            for (int r = 0; r < 4; ++r) {
                const int row = i * 16 + quad * 4 + r;
                const int col = j * 16 + mrow;
                Cg[(size_t)row * NN + col] = acc[i][j][r] * scale;
            }
        }
    }
}

// ---------------------------------------------------------------------------
// Launch
// ---------------------------------------------------------------------------
extern "C" void kernel_launch(void* const* d_in, const int* in_sizes, int n_in,
                              void* d_out, int out_size, void* d_ws, size_t ws_size,
                              hipStream_t stream) {
    const float* x   = (const float*)d_in[0];     // [4,1024,4096] fp32
    const int* pw    = (const int*)d_in[1];       // [11008*4096/4] int32
    const float* wsc = (const float*)d_in[2];     // [1] fp32

    float* out = (float*)d_out;                   // [4,1024,11008] fp32

    unsigned short* xb  = (unsigned short*)d_ws;                       // 32 MB
    unsigned short* pw2 = (unsigned short*)((char*)d_ws
                          + (size_t)M_DIM * IN_F * 2);                 // 22 MB

    // fused prep: 8192 cvt blocks + 688 repack blocks
    prep_kernel<<<8192 + 688, 256, 0, stream>>>(x, xb, pw, pw2);

    // GEMM: 688 tiles = 16 (M/256) x 43 (N/256), 512 threads (8 waves)
    gemm_kernel<<<688, 512, 0, stream>>>(xb, pw2, out, wsc);
}